// Round 10
// baseline (452.572 us; speedup 1.0000x reference)
//
#include <hip/hip_runtime.h>

// B=4, C=512, L=2048, H=8, D=64. f32 inputs, **f32 output** (proven by probe rounds 7/9).
// qkv = w_qkv^T @ x (f32 VALU GEMM, bf16 store) -> flash attn (bf16 MFMA) ->
// out = w_out^T @ ao + b_out (bf16 MFMA, f32 store).

#define LDIM 2048
#define CDIM 512
#define BATCH 4

typedef __attribute__((ext_vector_type(8))) short s16x8;
typedef __attribute__((ext_vector_type(4))) float f32x4;
typedef __attribute__((ext_vector_type(4))) unsigned short u16x4;
typedef unsigned short u16;

__device__ __forceinline__ u16 f2b(float f) {
    unsigned u = __float_as_uint(f);
    u += 0x7fffu + ((u >> 16) & 1u);   // RNE
    return (u16)(u >> 16);
}

// ---------------- QKV GEMM: f32 VALU, exact inputs, bf16 store ----------------
// Y[b][f][l] = sum_c W[c][f] * X[b][c][l].  64x64 tile, 256 thr, 4x4 per thread, BK=16.
__global__ __launch_bounds__(256)
void qkvgemm_f32(const float* __restrict__ X, const float* __restrict__ W,
                 u16* __restrict__ Y)
{
    const int f0 = blockIdx.x * 64;
    const int l0 = blockIdx.y * 64;
    const int b  = blockIdx.z;
    const float* Xb = X + (size_t)b * CDIM * LDIM;

    __shared__ __align__(16) float wt[16][68];  // [c_local][f_local]
    __shared__ __align__(16) float xt[16][68];  // [c_local][l_local]

    const int t  = threadIdx.x;
    const int sr = t >> 4;            // staging c row 0..15
    const int sc = (t & 15) * 4;      // staging col, f32x4
    const int tf = (t & 15) * 4;      // f_local base (4 outputs)
    const int tl = (t >> 4) * 4;      // l_local base (4 outputs)

    float acc[4][4] = {};

    for (int c0 = 0; c0 < CDIM; c0 += 16) {
        f32x4 wv = *(const f32x4*)(W  + (size_t)(c0 + sr) * 1536 + f0 + sc);
        f32x4 xv = *(const f32x4*)(Xb + (size_t)(c0 + sr) * LDIM + l0 + sc);
        __syncthreads();
        *(f32x4*)&wt[sr][sc] = wv;
        *(f32x4*)&xt[sr][sc] = xv;
        __syncthreads();
        #pragma unroll
        for (int kc = 0; kc < 16; ++kc) {
            f32x4 a  = *(const f32x4*)&wt[kc][tf];
            f32x4 bv = *(const f32x4*)&xt[kc][tl];
            #pragma unroll
            for (int i = 0; i < 4; ++i)
                #pragma unroll
                for (int j = 0; j < 4; ++j)
                    acc[i][j] += a[i] * bv[j];
        }
    }
    u16* Yb = Y + (size_t)b * 1536 * LDIM;
    #pragma unroll
    for (int i = 0; i < 4; ++i) {
        u16x4 pk;
        #pragma unroll
        for (int j = 0; j < 4; ++j) pk[j] = f2b(acc[i][j]);
        *(u16x4*)(Yb + (size_t)(f0 + tf + i) * LDIM + l0 + tl) = pk;
    }
}

// ---------------- Output GEMM: bf16 MFMA, f32 store ----------------
// Y[b][f][l] = sum_c W[c][f] * X[b][c][l] + bias[f].  X bf16 (ao), W f32, Y f32.
__global__ __launch_bounds__(256)
void outgemm_k(const u16* __restrict__ X, const float* __restrict__ W,
               const float* __restrict__ bias, float* __restrict__ Y)
{
    const int FD = 512;
    const int f0 = blockIdx.x * 64;
    const int l0 = blockIdx.y * 64;
    const int b  = blockIdx.z;
    const u16* Xb = X + (size_t)b * CDIM * LDIM;
    float* Yb = Y + (size_t)b * FD * LDIM;

    __shared__ __align__(16) u16 lds_a[64][56];  // [f_local][c_local]
    __shared__ __align__(16) u16 lds_b[64][56];  // [l_local][c_local]

    const int tid  = threadIdx.x;
    const int wave = tid >> 6, lane = tid & 63;
    const int wm = (wave >> 1) * 32;
    const int wn = (wave & 1) * 32;
    const int mn = lane & 15, q = lane >> 4;

    const int sr = tid >> 3;        // c row 0..31
    const int sc = (tid & 7) * 8;   // col 0..56 step 8

    f32x4 acc[2][2] = {};

    for (int c0 = 0; c0 < CDIM; c0 += 32) {
        // W (f32) -> bf16 x8
        f32x4 wa = *(const f32x4*)(W + (size_t)(c0 + sr) * FD + f0 + sc);
        f32x4 wb = *(const f32x4*)(W + (size_t)(c0 + sr) * FD + f0 + sc + 4);
        s16x8 xv = *(const s16x8*)(Xb + (size_t)(c0 + sr) * LDIM + l0 + sc);
        u16 av[8];
        av[0]=f2b(wa[0]); av[1]=f2b(wa[1]); av[2]=f2b(wa[2]); av[3]=f2b(wa[3]);
        av[4]=f2b(wb[0]); av[5]=f2b(wb[1]); av[6]=f2b(wb[2]); av[7]=f2b(wb[3]);
        __syncthreads();
        #pragma unroll
        for (int j = 0; j < 8; ++j) {
            lds_a[sc + j][sr] = av[j];
            lds_b[sc + j][sr] = (u16)xv[j];
        }
        __syncthreads();
        #pragma unroll
        for (int fi = 0; fi < 2; ++fi) {
            s16x8 af = *(const s16x8*)(&lds_a[wm + fi * 16 + mn][q * 8]);
            #pragma unroll
            for (int lj = 0; lj < 2; ++lj) {
                s16x8 bf = *(const s16x8*)(&lds_b[wn + lj * 16 + mn][q * 8]);
                acc[fi][lj] = __builtin_amdgcn_mfma_f32_16x16x32_bf16(af, bf, acc[fi][lj], 0, 0, 0);
            }
        }
    }
    #pragma unroll
    for (int fi = 0; fi < 2; ++fi)
        #pragma unroll
        for (int lj = 0; lj < 2; ++lj)
            #pragma unroll
            for (int r = 0; r < 4; ++r) {
                int fg = f0 + wm + fi * 16 + q * 4 + r;
                int lg = l0 + wn + lj * 16 + mn;
                Yb[(size_t)fg * LDIM + lg] = acc[fi][lj][r] + bias[fg];
            }
}

// ---------------- Flash attention (bf16 MFMA), unchanged from round 6 ----------------
__global__ __launch_bounds__(256)
void attn_k(const u16* __restrict__ QKV, u16* __restrict__ AO)
{
    const int i0 = blockIdx.x * 128;
    const int bh = blockIdx.y;
    const int b = bh >> 3, h = bh & 7;
    const u16* Q = QKV + ((size_t)b * 1536 + h * 64) * LDIM;
    const u16* K = Q + (size_t)512 * LDIM;
    const u16* V = Q + (size_t)1024 * LDIM;
    u16* O = AO + ((size_t)b * 512 + h * 64) * LDIM;

    __shared__ __align__(16) u16 lds_q[128][72];  // [i][d]
    __shared__ __align__(16) u16 lds_k[64][72];   // [j][d]
    __shared__ __align__(16) u16 lds_p[128][72];  // [i][j_local]

    const int tid  = threadIdx.x;
    const int wave = tid >> 6, lane = tid & 63;
    const int mn = lane & 15, q = lane >> 4;
    const int iw = wave * 32;

    {   // stage Q^T once: [d][i] -> [i][d]
        int d  = tid >> 2;
        int ib = (tid & 3) * 32;
        #pragma unroll
        for (int u = 0; u < 4; ++u) {
            s16x8 v = *(const s16x8*)(Q + (size_t)d * LDIM + i0 + ib + u * 8);
            #pragma unroll
            for (int j = 0; j < 8; ++j)
                lds_q[ib + u * 8 + j][d] = (u16)v[j];
        }
    }
    __syncthreads();
    s16x8 aq[2][2];
    #pragma unroll
    for (int ibt = 0; ibt < 2; ++ibt)
        #pragma unroll
        for (int kd = 0; kd < 2; ++kd)
            aq[ibt][kd] = *(const s16x8*)(&lds_q[iw + ibt * 16 + mn][kd * 32 + q * 8]);

    f32x4 o_acc[2][4] = {};
    float m2[2][4], lsum[2][4];
    #pragma unroll
    for (int a = 0; a < 2; ++a)
        #pragma unroll
        for (int r = 0; r < 4; ++r) { m2[a][r] = -1e30f; lsum[a][r] = 0.f; }

    const float SC2 = 0.125f * 1.4426950408889634f;

    for (int j0 = 0; j0 < LDIM; j0 += 64) {
        __syncthreads();
        {   // stage K tile: [d][j] -> lds_k[j][d]
            int d  = tid >> 2;
            int jb = (tid & 3) * 16;
            #pragma unroll
            for (int u = 0; u < 2; ++u) {
                s16x8 v = *(const s16x8*)(K + (size_t)d * LDIM + j0 + jb + u * 8);
                #pragma unroll
                for (int j = 0; j < 8; ++j)
                    lds_k[jb + u * 8 + j][d] = (u16)v[j];
            }
        }
        __syncthreads();

        f32x4 s[2][4] = {};
        #pragma unroll
        for (int kd = 0; kd < 2; ++kd)
            #pragma unroll
            for (int jt = 0; jt < 4; ++jt) {
                s16x8 bk = *(const s16x8*)(&lds_k[jt * 16 + mn][kd * 32 + q * 8]);
                s[0][jt] = __builtin_amdgcn_mfma_f32_16x16x32_bf16(aq[0][kd], bk, s[0][jt], 0, 0, 0);
                s[1][jt] = __builtin_amdgcn_mfma_f32_16x16x32_bf16(aq[1][kd], bk, s[1][jt], 0, 0, 0);
            }

        #pragma unroll
        for (int ibt = 0; ibt < 2; ++ibt)
            #pragma unroll
            for (int r = 0; r < 4; ++r) {
                float t0 = s[ibt][0][r] * SC2;
                float t1 = s[ibt][1][r] * SC2;
                float t2 = s[ibt][2][r] * SC2;
                float t3 = s[ibt][3][r] * SC2;
                float rm = fmaxf(fmaxf(t0, t1), fmaxf(t2, t3));
                #pragma unroll
                for (int off = 8; off >= 1; off >>= 1)
                    rm = fmaxf(rm, __shfl_xor(rm, off));
                float mnew  = fmaxf(m2[ibt][r], rm);
                float alpha = exp2f(m2[ibt][r] - mnew);
                m2[ibt][r] = mnew;
                float p0 = exp2f(t0 - mnew);
                float p1 = exp2f(t1 - mnew);
                float p2 = exp2f(t2 - mnew);
                float p3 = exp2f(t3 - mnew);
                int irow = iw + ibt * 16 + q * 4 + r;
                lds_p[irow][ 0 + mn] = f2b(p0);
                lds_p[irow][16 + mn] = f2b(p1);
                lds_p[irow][32 + mn] = f2b(p2);
                lds_p[irow][48 + mn] = f2b(p3);
                float ps = p0 + p1 + p2 + p3;
                #pragma unroll
                for (int off = 8; off >= 1; off >>= 1)
                    ps += __shfl_xor(ps, off);
                lsum[ibt][r] = lsum[ibt][r] * alpha + ps;
                #pragma unroll
                for (int dt = 0; dt < 4; ++dt)
                    o_acc[ibt][dt][r] *= alpha;
            }

        s16x8 ap[2][2];
        #pragma unroll
        for (int ibt = 0; ibt < 2; ++ibt)
            #pragma unroll
            for (int kj = 0; kj < 2; ++kj)
                ap[ibt][kj] = *(const s16x8*)(&lds_p[iw + ibt * 16 + mn][kj * 32 + q * 8]);
        #pragma unroll
        for (int kj = 0; kj < 2; ++kj)
            #pragma unroll
            for (int dt = 0; dt < 4; ++dt) {
                s16x8 bv = *(const s16x8*)(V + (size_t)(dt * 16 + mn) * LDIM + j0 + kj * 32 + q * 8);
                o_acc[0][dt] = __builtin_amdgcn_mfma_f32_16x16x32_bf16(ap[0][kj], bv, o_acc[0][dt], 0, 0, 0);
                o_acc[1][dt] = __builtin_amdgcn_mfma_f32_16x16x32_bf16(ap[1][kj], bv, o_acc[1][dt], 0, 0, 0);
            }
    }

    #pragma unroll
    for (int ibt = 0; ibt < 2; ++ibt)
        #pragma unroll
        for (int dt = 0; dt < 4; ++dt) {
            u16x4 pk;
            #pragma unroll
            for (int r = 0; r < 4; ++r)
                pk[r] = f2b(o_acc[ibt][dt][r] / lsum[ibt][r]);
            int d  = dt * 16 + mn;
            int il = i0 + iw + ibt * 16 + q * 4;
            *(u16x4*)(O + (size_t)d * LDIM + il) = pk;
        }
}

extern "C" void kernel_launch(void* const* d_in, const int* in_sizes, int n_in,
                              void* d_out, int out_size, void* d_ws, size_t ws_size,
                              hipStream_t stream) {
    const float *x = nullptr, *w_qkv = nullptr, *w_out = nullptr, *b_out = nullptr;
    for (int i = 0; i < n_in; ++i) {
        switch (in_sizes[i]) {
            case 4 * 512 * 2048: x     = (const float*)d_in[i]; break;
            case 512 * 1536:     w_qkv = (const float*)d_in[i]; break;
            case 512 * 512:      w_out = (const float*)d_in[i]; break;
            case 512:            b_out = (const float*)d_in[i]; break;
        }
    }
    float* out = (float*)d_out;                     // [4][512][2048] f32 (!)

    u16* qkv = (u16*)d_ws;                          // [4][1536][2048] bf16 = 25.2 MB
    u16* ao  = qkv + (size_t)BATCH * 1536 * LDIM;   // [4][512][2048]  bf16 =  8.4 MB

    qkvgemm_f32<<<dim3(1536 / 64, LDIM / 64, BATCH), 256, 0, stream>>>(x, w_qkv, qkv);
    attn_k<<<dim3(LDIM / 128, BATCH * 8), 256, 0, stream>>>(qkv, ao);
    outgemm_k<<<dim3(512 / 64, LDIM / 64, BATCH), 256, 0, stream>>>(ao, w_out, b_out, out);
}